// Round 6
// baseline (186.978 us; speedup 1.0000x reference)
//
#include <hip/hip_runtime.h>
#include <hip/hip_bf16.h>
#include <stdint.h>

#define N_B 4
#define NV 4096
#define NE 2048
#define NC 64

typedef float    f32x4  __attribute__((ext_vector_type(4)));
typedef __bf16   bf16x8 __attribute__((ext_vector_type(8)));
typedef unsigned short u16;
typedef u16      u16x8  __attribute__((ext_vector_type(8)));
typedef uint32_t u32x4  __attribute__((ext_vector_type(4)));

__device__ __forceinline__ u16 f2bf_rne(float f) {
    uint32_t u = __builtin_bit_cast(uint32_t, f);
    u += 0x7FFFu + ((u >> 16) & 1u);
    return (u16)(u >> 16);
}
__device__ __forceinline__ float bf2f(u16 h) {
    uint32_t u = ((uint32_t)h) << 16;
    return __builtin_bit_cast(float, u);
}
__device__ __forceinline__ f32x4 mfma_bf16(u16x8 a, u16x8 b, f32x4 c) {
    return __builtin_amdgcn_mfma_f32_16x16x32_bf16(
        __builtin_bit_cast(bf16x8, a), __builtin_bit_cast(bf16x8, b), c, 0, 0, 0);
}

// ---------------------------------------------------------------------------
// Kernel 1: Yht_{h,l}[n][c][v] (bf16 hi/lo) = transpose of x@theta.
// ---------------------------------------------------------------------------
__global__ __launch_bounds__(256) void k_xtheta(const float* __restrict__ x,
                                                const float* __restrict__ th,
                                                u16* __restrict__ Yh,
                                                u16* __restrict__ Yl) {
    __shared__ float xs[64][65];   // [v][k]
    __shared__ float ts[64][65];   // [k][c]
    const int t = threadIdx.x;
    const int n  = blockIdx.x >> 6;
    const int v0 = (blockIdx.x & 63) * 64;

#pragma unroll
    for (int i = 0; i < 4; ++i) {
        const int idx = i * 256 + t;
        const int row = idx >> 4, q = (idx & 15) * 4;
        const float4 xv = *(const float4*)&x[((size_t)(n * NV + v0 + row)) * 64 + q];
        const float4 tv = *(const float4*)&th[(size_t)row * 64 + q];
        xs[row][q] = xv.x; xs[row][q + 1] = xv.y; xs[row][q + 2] = xv.z; xs[row][q + 3] = xv.w;
        ts[row][q] = tv.x; ts[row][q + 1] = tv.y; ts[row][q + 2] = tv.z; ts[row][q + 3] = tv.w;
    }
    __syncthreads();

    const int v4 = (t & 15) * 4;
    const int c4 = (t >> 4) * 4;
    float acc[4][4] = {};   // [c][v]
#pragma unroll
    for (int k = 0; k < 64; ++k) {
        float tv[4], xv[4];
#pragma unroll
        for (int i = 0; i < 4; ++i) { tv[i] = ts[k][c4 + i]; xv[i] = xs[v4 + i][k]; }
#pragma unroll
        for (int i = 0; i < 4; ++i)
#pragma unroll
            for (int j = 0; j < 4; ++j) acc[i][j] += tv[i] * xv[j];
    }
#pragma unroll
    for (int i = 0; i < 4; ++i) {
        ushort4 hi, lo;
        u16 h;
        h = f2bf_rne(acc[i][0]); hi.x = h; lo.x = f2bf_rne(acc[i][0] - bf2f(h));
        h = f2bf_rne(acc[i][1]); hi.y = h; lo.y = f2bf_rne(acc[i][1] - bf2f(h));
        h = f2bf_rne(acc[i][2]); hi.z = h; lo.z = f2bf_rne(acc[i][2] - bf2f(h));
        h = f2bf_rne(acc[i][3]); hi.w = h; lo.w = f2bf_rne(acc[i][3] - bf2f(h));
        const size_t o = ((size_t)n * 64 + c4 + i) * NV + v0 + v4;
        *(ushort4*)&Yh[o] = hi;
        *(ushort4*)&Yl[o] = lo;
    }
}

// ---------------------------------------------------------------------------
// Kernel 2: vertex->edge MFMA partials.
//   P2[sp][n][c][e] = sum_{v in Krange} H[n,v,e]*(Yh+Yl)[n,v,c]
//   deP[sp][n][e]   = sum H (constant all-ones B fragment)
// Block 64e x 64c, 4 waves. K-step 32 v.
// A = H^T via LDS transpose (80B rows). B = Y^T at-use (L2-resident).
// Depth-1 reg-prefetch ONLY for H (the HBM stream). VGPR pinned <=64.
// ---------------------------------------------------------------------------
__global__ __launch_bounds__(256, 8) void k_v2e(const float* __restrict__ H,
                                                const u16* __restrict__ Yh,
                                                const u16* __restrict__ Yl,
                                                float* __restrict__ P2,
                                                float* __restrict__ deP) {
    __shared__ u16 Hlds[64 * 40];   // [e][40 bf16 slots], 80B rows, 5 KB

    const int n   = blockIdx.z;
    const int e0  = blockIdx.x * 64;
    const int sp  = blockIdx.y;
    const int krange = NV / gridDim.y;
    const int kk0 = sp * krange;
    const int S   = krange / 32;

    const int t  = threadIdx.x;
    const int w  = t >> 6, l = t & 63;
    const int lq = l >> 4, lr = l & 15;

    const float* __restrict__ Hn = H + (size_t)n * NV * NE;

    // staging role: v-pair sr (rows 2sr,2sr+1), e-chunk sec (4 e)
    const int sr  = t & 15;
    const int sec = t >> 4;

    const u16* __restrict__ ybh = Yh + ((size_t)n * 64 + lr) * NV + lq * 8;
    const u16* __restrict__ ybl = Yl + ((size_t)n * 64 + lr) * NV + lq * 8;

    f32x4 acc0 = {0.f,0.f,0.f,0.f}, acc1 = acc0, acc2 = acc0, acc3 = acc0, accd = acc0;
    const u16x8 bones = {0x3F80,0x3F80,0x3F80,0x3F80,0x3F80,0x3F80,0x3F80,0x3F80};

    // prologue H loads (step 0)
    const float* hs0 = Hn + (size_t)(kk0 + 2 * sr) * NE + e0 + sec * 4;
    float4 ha = *(const float4*)hs0;
    float4 hb = *(const float4*)(hs0 + NE);

    const int a_off = (w * 16 + lr) * 40 + lq * 8;

    for (int s = 0; s < S; ++s) {
        __syncthreads();   // previous step's A-reads done
        {
            uint32_t* hw = (uint32_t*)Hlds;
            const uint32_t* pa = (const uint32_t*)&ha;
            const uint32_t* pb = (const uint32_t*)&hb;
#pragma unroll
            for (int i = 0; i < 4; ++i) {
                const uint32_t v = (pa[i] >> 16) | (pb[i] & 0xFFFF0000u);
                hw[(sec * 4 + i) * 20 + sr] = v;
            }
        }
        __syncthreads();

        // prefetch next-step H (HBM latency hidden under MFMA phase)
        float4 han, hbn;
        if (s + 1 < S) {
            const float* hs = Hn + (size_t)(kk0 + (s + 1) * 32 + 2 * sr) * NE + e0 + sec * 4;
            han = *(const float4*)hs;
            hbn = *(const float4*)(hs + NE);
        }

        const u16x8 afrag = *(const u16x8*)(Hlds + a_off);
        const int vk = kk0 + s * 32;

        // B fragments loaded at use (L2-resident Y; 8 waves/SIMD cover latency)
        u16x8 bh, bl;
        bh = *(const u16x8*)(ybh + vk);
        bl = *(const u16x8*)(ybl + vk);
        acc0 = mfma_bf16(afrag, bh, acc0);
        acc0 = mfma_bf16(afrag, bl, acc0);
        bh = *(const u16x8*)(ybh + 16 * NV + vk);
        bl = *(const u16x8*)(ybl + 16 * NV + vk);
        acc1 = mfma_bf16(afrag, bh, acc1);
        acc1 = mfma_bf16(afrag, bl, acc1);
        bh = *(const u16x8*)(ybh + 32 * NV + vk);
        bl = *(const u16x8*)(ybl + 32 * NV + vk);
        acc2 = mfma_bf16(afrag, bh, acc2);
        acc2 = mfma_bf16(afrag, bl, acc2);
        bh = *(const u16x8*)(ybh + 48 * NV + vk);
        bl = *(const u16x8*)(ybl + 48 * NV + vk);
        acc3 = mfma_bf16(afrag, bh, acc3);
        acc3 = mfma_bf16(afrag, bl, acc3);
        accd = mfma_bf16(afrag, bones, accd);

        if (s + 1 < S) { ha = han; hb = hbn; }
    }

    // D frag: row e = e0 + w*16 + lq*4 + r, col c = f*16 + lr
    const int e_lane = e0 + w * 16 + lq * 4;
    float* pbase = P2 + (((size_t)sp * N_B + n) * 64) * NE;
    *(f32x4*)&pbase[(size_t)(0 * 16 + lr) * NE + e_lane] = acc0;
    *(f32x4*)&pbase[(size_t)(1 * 16 + lr) * NE + e_lane] = acc1;
    *(f32x4*)&pbase[(size_t)(2 * 16 + lr) * NE + e_lane] = acc2;
    *(f32x4*)&pbase[(size_t)(3 * 16 + lr) * NE + e_lane] = acc3;
    if (lr == 0)
        *(f32x4*)&deP[((size_t)sp * N_B + n) * NE + e_lane] = accd;
}

// ---------------------------------------------------------------------------
// Kernel 3: Z_{h,l}[n][c][e] = bf16 hi/lo of (sum_sp P2)/de
// ---------------------------------------------------------------------------
__global__ __launch_bounds__(256) void k_red2(const float* __restrict__ P2,
                                              const float* __restrict__ deP,
                                              u16* __restrict__ Zh,
                                              u16* __restrict__ Zl, int nsp) {
    const int i = blockIdx.x * 256 + threadIdx.x;   // 0..131071
    const int row = i >> 9;                          // n*64 + c
    const int e4  = (i & 511) * 4;
    const int n   = row >> 6;

    float4 a = make_float4(0.f, 0.f, 0.f, 0.f);
    float4 d = make_float4(0.f, 0.f, 0.f, 0.f);
    for (int sp = 0; sp < nsp; ++sp) {
        const float4 p = *(const float4*)&P2[((size_t)sp * 256 + row) * NE + e4];
        const float4 q = *(const float4*)&deP[((size_t)sp * N_B + n) * NE + e4];
        a.x += p.x; a.y += p.y; a.z += p.z; a.w += p.w;
        d.x += q.x; d.y += q.y; d.z += q.z; d.w += q.w;
    }
    float z[4] = {a.x / d.x, a.y / d.y, a.z / d.z, a.w / d.w};
    ushort4 hi, lo;
    u16 h;
    h = f2bf_rne(z[0]); hi.x = h; lo.x = f2bf_rne(z[0] - bf2f(h));
    h = f2bf_rne(z[1]); hi.y = h; lo.y = f2bf_rne(z[1] - bf2f(h));
    h = f2bf_rne(z[2]); hi.z = h; lo.z = f2bf_rne(z[2] - bf2f(h));
    h = f2bf_rne(z[3]); hi.w = h; lo.w = f2bf_rne(z[3] - bf2f(h));
    *(ushort4*)&Zh[(size_t)row * NE + e4] = hi;
    *(ushort4*)&Zl[(size_t)row * NE + e4] = lo;
}

// ---------------------------------------------------------------------------
// Kernel 4: edge->vertex MFMA partials. NO LDS, no barriers.
//   P3[sp][n][c][v] = sum_{e in Krange} H[n,v,e]*(Zh+Zl)[n,e,c]
//   dvP[sp][n][v]   = sum H (ones fragment)
// A = H direct (k=e contiguous), depth-1 reg prefetch (HBM stream).
// B = Z^T at-use (L2-resident). VGPR pinned <=64.
// ---------------------------------------------------------------------------
__global__ __launch_bounds__(256, 8) void k_e2v(const float* __restrict__ H,
                                                const u16* __restrict__ Zh,
                                                const u16* __restrict__ Zl,
                                                float* __restrict__ P3,
                                                float* __restrict__ dvP) {
    const int n   = blockIdx.z;
    const int v0  = blockIdx.x * 64;
    const int sp  = blockIdx.y;
    const int krange = NE / gridDim.y;
    const int kk0 = sp * krange;
    const int S   = krange / 32;

    const int t  = threadIdx.x;
    const int w  = t >> 6, l = t & 63;
    const int lq = l >> 4, lr = l & 15;

    const int vrow = v0 + w * 16 + lr;
    const float* __restrict__ ap = H + ((size_t)n * NV + vrow) * NE + lq * 8;
    const u16* __restrict__ zbh = Zh + ((size_t)n * 64 + lr) * NE + lq * 8;
    const u16* __restrict__ zbl = Zl + ((size_t)n * 64 + lr) * NE + lq * 8;

    f32x4 acc0 = {0.f,0.f,0.f,0.f}, acc1 = acc0, acc2 = acc0, acc3 = acc0, accd = acc0;
    const u16x8 bones = {0x3F80,0x3F80,0x3F80,0x3F80,0x3F80,0x3F80,0x3F80,0x3F80};

    float4 a0 = *(const float4*)(ap + kk0);
    float4 a1 = *(const float4*)(ap + kk0 + 4);

    for (int s = 0; s < S; ++s) {
        // prefetch next-step H (HBM stream)
        float4 a0n, a1n;
        if (s + 1 < S) {
            const int en = kk0 + (s + 1) * 32;
            a0n = *(const float4*)(ap + en);
            a1n = *(const float4*)(ap + en + 4);
        }

        const uint32_t* u0 = (const uint32_t*)&a0;
        const uint32_t* u1 = (const uint32_t*)&a1;
        const u32x4 aw = { (u0[0] >> 16) | (u0[1] & 0xFFFF0000u),
                           (u0[2] >> 16) | (u0[3] & 0xFFFF0000u),
                           (u1[0] >> 16) | (u1[1] & 0xFFFF0000u),
                           (u1[2] >> 16) | (u1[3] & 0xFFFF0000u) };
        const u16x8 afrag = __builtin_bit_cast(u16x8, aw);

        const int ek = kk0 + s * 32;
        u16x8 bh, bl;
        bh = *(const u16x8*)(zbh + ek);
        bl = *(const u16x8*)(zbl + ek);
        acc0 = mfma_bf16(afrag, bh, acc0);
        acc0 = mfma_bf16(afrag, bl, acc0);
        bh = *(const u16x8*)(zbh + 16 * NE + ek);
        bl = *(const u16x8*)(zbl + 16 * NE + ek);
        acc1 = mfma_bf16(afrag, bh, acc1);
        acc1 = mfma_bf16(afrag, bl, acc1);
        bh = *(const u16x8*)(zbh + 32 * NE + ek);
        bl = *(const u16x8*)(zbl + 32 * NE + ek);
        acc2 = mfma_bf16(afrag, bh, acc2);
        acc2 = mfma_bf16(afrag, bl, acc2);
        bh = *(const u16x8*)(zbh + 48 * NE + ek);
        bl = *(const u16x8*)(zbl + 48 * NE + ek);
        acc3 = mfma_bf16(afrag, bh, acc3);
        acc3 = mfma_bf16(afrag, bl, acc3);
        accd = mfma_bf16(afrag, bones, accd);

        if (s + 1 < S) { a0 = a0n; a1 = a1n; }
    }

    // D frag: row v = v0 + w*16 + lq*4 + r, col c = f*16 + lr
    const int v_lane = v0 + w * 16 + lq * 4;
    float* pbase = P3 + (((size_t)sp * N_B + n) * 64) * NV;
    *(f32x4*)&pbase[(size_t)(0 * 16 + lr) * NV + v_lane] = acc0;
    *(f32x4*)&pbase[(size_t)(1 * 16 + lr) * NV + v_lane] = acc1;
    *(f32x4*)&pbase[(size_t)(2 * 16 + lr) * NV + v_lane] = acc2;
    *(f32x4*)&pbase[(size_t)(3 * 16 + lr) * NV + v_lane] = acc3;
    if (lr == 0)
        *(f32x4*)&dvP[((size_t)sp * N_B + n) * NV + v_lane] = accd;
}

// ---------------------------------------------------------------------------
// Kernel 5: out[n][v][c] = (sum_sp P3[sp][n][c][v]) / dv + bias  (transpose)
// ---------------------------------------------------------------------------
__global__ __launch_bounds__(512) void k_red3(const float* __restrict__ P3,
                                              const float* __restrict__ dvP,
                                              const float* __restrict__ bias,
                                              float* __restrict__ out, int nsp) {
    __shared__ float lt[64][68];
    const int n  = blockIdx.y;
    const int v0 = blockIdx.x * 64;
    const int t  = threadIdx.x;

    {
        const int c   = t >> 3;
        const int vch = (t & 7) * 8;
        float4 s0 = make_float4(0.f, 0.f, 0.f, 0.f), s1 = s0;
        for (int sp = 0; sp < nsp; ++sp) {
            const size_t base = (((size_t)sp * N_B + n) * 64 + c) * NV + v0 + vch;
            const float4 p0 = *(const float4*)&P3[base];
            const float4 p1 = *(const float4*)&P3[base + 4];
            s0.x += p0.x; s0.y += p0.y; s0.z += p0.z; s0.w += p0.w;
            s1.x += p1.x; s1.y += p1.y; s1.z += p1.z; s1.w += p1.w;
        }
        *(float4*)&lt[c][vch]     = s0;
        *(float4*)&lt[c][vch + 4] = s1;
    }
    const int vw  = t >> 3;
    const int cch = (t & 7) * 8;
    float dsum = 0.f;
    for (int sp = 0; sp < nsp; ++sp)
        dsum += dvP[((size_t)sp * N_B + n) * NV + v0 + vw];
    __syncthreads();

    const float rdv = 1.0f / dsum;
    const float4 b0 = *(const float4*)&bias[cch];
    const float4 b1 = *(const float4*)&bias[cch + 4];
    float4 o0, o1;
    o0.x = lt[cch + 0][vw] * rdv + b0.x;
    o0.y = lt[cch + 1][vw] * rdv + b0.y;
    o0.z = lt[cch + 2][vw] * rdv + b0.z;
    o0.w = lt[cch + 3][vw] * rdv + b0.w;
    o1.x = lt[cch + 4][vw] * rdv + b1.x;
    o1.y = lt[cch + 5][vw] * rdv + b1.y;
    o1.z = lt[cch + 6][vw] * rdv + b1.z;
    o1.w = lt[cch + 7][vw] * rdv + b1.w;
    float* dst = out + ((size_t)n * NV + v0 + vw) * 64 + cch;
    *(float4*)dst       = o0;
    *(float4*)(dst + 4) = o1;
}

// ---------------------------------------------------------------------------
extern "C" void kernel_launch(void* const* d_in, const int* in_sizes, int n_in,
                              void* d_out, int out_size, void* d_ws, size_t ws_size,
                              hipStream_t stream) {
    const float* x     = (const float*)d_in[0];
    const float* H     = (const float*)d_in[1];
    const float* theta = (const float*)d_in[2];
    const float* bias  = (const float*)d_in[3];
    float* out = (float*)d_out;

    const size_t yE  = (size_t)N_B * 64 * NV;   // 1,048,576 elems
    const size_t zE  = (size_t)N_B * 64 * NE;   //   524,288
    const size_t deE = (size_t)N_B * NE;
    const size_t dvE = (size_t)N_B * NV;

    u16* Yh = (u16*)d_ws;
    u16* Yl = Yh + yE;
    u16* Zh = Yl + yE;
    u16* Zl = Zh + zE;
    float* fbase = (float*)(Zl + zE);
    const size_t fixed_bytes = (2 * yE + 2 * zE) * sizeof(u16);
    const size_t avail_f = (ws_size > fixed_bytes) ? (ws_size - fixed_bytes) / 4 : 0;

    const size_t unit2 = zE + deE;   // per s2 (floats)
    const size_t unit3 = yE + dvE;   // per s3 (floats)
    int s2 = 1, s3 = 1;
    if      (avail_f >= 16 * unit2 + 8 * unit3) { s2 = 16; s3 = 8; }
    else if (avail_f >= 16 * unit2 + 4 * unit3) { s2 = 16; s3 = 4; }
    else if (avail_f >=  8 * unit2 + 4 * unit3) { s2 = 8;  s3 = 4; }
    else if (avail_f >=  4 * unit2 + 2 * unit3) { s2 = 4;  s3 = 2; }
    else if (avail_f >=  2 * unit2 + 1 * unit3) { s2 = 2;  s3 = 1; }

    float* P2  = fbase;
    float* deP = P2 + (size_t)s2 * zE;
    float* P3  = deP + (size_t)s2 * deE;
    float* dvP = P3 + (size_t)s3 * yE;

    k_xtheta<<<dim3(N_B * NV / 64), 256, 0, stream>>>(x, theta, Yh, Yl);
    k_v2e<<<dim3(NE / 64, s2, N_B), 256, 0, stream>>>(H, Yh, Yl, P2, deP);
    k_red2<<<dim3((int)(zE / 4 / 256)), 256, 0, stream>>>(P2, deP, Zh, Zl, s2);
    k_e2v<<<dim3(NV / 64, s3, N_B), 256, 0, stream>>>(H, Zh, Zl, P3, dvP);
    k_red3<<<dim3(NV / 64, N_B), 512, 0, stream>>>(P3, dvP, bias, out, s3);
}

// Round 7
// 120.233 us; speedup vs baseline: 1.5551x; 1.5551x over previous
//
#include <hip/hip_runtime.h>
#include <hip/hip_bf16.h>
#include <stdint.h>

#define N_B 4
#define NV 4096
#define NE 2048
#define NC 64

typedef float    f32x4  __attribute__((ext_vector_type(4)));
typedef __bf16   bf16x8 __attribute__((ext_vector_type(8)));
typedef unsigned short u16;
typedef u16      u16x8  __attribute__((ext_vector_type(8)));
typedef uint32_t u32x4  __attribute__((ext_vector_type(4)));

__device__ __forceinline__ u16 f2bf_rne(float f) {
    uint32_t u = __builtin_bit_cast(uint32_t, f);
    u += 0x7FFFu + ((u >> 16) & 1u);
    return (u16)(u >> 16);
}
__device__ __forceinline__ float bf2f(u16 h) {
    uint32_t u = ((uint32_t)h) << 16;
    return __builtin_bit_cast(float, u);
}
__device__ __forceinline__ f32x4 mfma_bf16(u16x8 a, u16x8 b, f32x4 c) {
    return __builtin_amdgcn_mfma_f32_16x16x32_bf16(
        __builtin_bit_cast(bf16x8, a), __builtin_bit_cast(bf16x8, b), c, 0, 0, 0);
}
// 8 bits -> 8 bf16 (1.0/0.0). u16 lane j = bit j.
__device__ __forceinline__ u16x8 expand8(uint32_t byte) {
    u32x4 w;
#pragma unroll
    for (int p = 0; p < 4; ++p) {
        const uint32_t lo = (byte >> (2 * p)) & 1u;
        const uint32_t hi = (byte >> (2 * p + 1)) & 1u;
        w[p] = (lo | (hi << 16)) * 0x3F80u;
    }
    return __builtin_bit_cast(u16x8, w);
}

// ---------------------------------------------------------------------------
// Kernel P: pack H (fp32 0/1) into bitmasks, both orientations, + degree
// partials via popcount.
//   HB[n][v>>4][e/32][v&15]  (bit = e&31)
//   HT[n][e>>4][v/32][e&15]  (bit = v&31)
//   dvP[et][n][v] = popcount over 64-e strip;  deP[vt][n][e] over 64-v strip
// grid (NE/64, NV/64, N_B), 256 threads.
// ---------------------------------------------------------------------------
__global__ __launch_bounds__(256) void k_pack(const float* __restrict__ H,
                                              uint32_t* __restrict__ HB,
                                              uint32_t* __restrict__ HT,
                                              float* __restrict__ dvP,
                                              float* __restrict__ deP) {
    __shared__ float tile[64][65];
    const int n  = blockIdx.z;
    const int v0 = blockIdx.y * 64;
    const int e0 = blockIdx.x * 64;
    const int t = threadIdx.x, w = t >> 6, l = t & 63;

    const float* __restrict__ Hn = H + ((size_t)n * NV + v0) * NE + e0;

    // Phase A: row ballots (bits across e) -> HB, dv partials
#pragma unroll 4
    for (int i = 0; i < 16; ++i) {
        const int row = w * 16 + i;
        const float h = Hn[(size_t)row * NE + l];
        tile[row][l] = h;
        const unsigned long long m = __ballot(h != 0.0f);
        if (l == 0)
            dvP[((size_t)blockIdx.x * N_B + n) * NV + v0 + row] = (float)__popcll(m);
        if (l < 2)
            HB[(((size_t)n * (NV / 16) + ((v0 + row) >> 4)) * (NE / 32) + (e0 >> 5) + l) * 16 +
               ((v0 + row) & 15)] = (uint32_t)(m >> (32 * l));
    }
    __syncthreads();

    // Phase B: column ballots (bits across v) -> HT, de partials
#pragma unroll 4
    for (int i = 0; i < 16; ++i) {
        const int col = w * 16 + i;
        const float h = tile[l][col];   // bank (l+col)%32: 2-way, free
        const unsigned long long m = __ballot(h != 0.0f);
        if (l == 0)
            deP[((size_t)blockIdx.y * N_B + n) * NE + e0 + col] = (float)__popcll(m);
        if (l < 2)
            HT[(((size_t)n * (NE / 16) + ((e0 + col) >> 4)) * (NV / 32) + (v0 >> 5) + l) * 16 +
               ((e0 + col) & 15)] = (uint32_t)(m >> (32 * l));
    }
}

// ---------------------------------------------------------------------------
// Kernel D: collapse degree partials.  de[n][e] = sum_vt deP; dv[n][v] = sum_et dvP
// ---------------------------------------------------------------------------
__global__ __launch_bounds__(256) void k_deg(const float* __restrict__ dvP,
                                             const float* __restrict__ deP,
                                             float* __restrict__ dv,
                                             float* __restrict__ de) {
    const int id = blockIdx.x * 256 + threadIdx.x;
    if (id < N_B * NE) {
        float s = 0.f;
        for (int vt = 0; vt < 64; ++vt) s += deP[(size_t)vt * (N_B * NE) + id];
        de[id] = s;
    } else {
        const int j = id - N_B * NE;   // < N_B*NV by grid sizing
        float s = 0.f;
        for (int et = 0; et < 32; ++et) s += dvP[(size_t)et * (N_B * NV) + j];
        dv[j] = s;
    }
}

// ---------------------------------------------------------------------------
// Kernel 1: Yht_{h,l}[n][c][v] (bf16 hi/lo) = transpose of x@theta.
// ---------------------------------------------------------------------------
__global__ __launch_bounds__(256) void k_xtheta(const float* __restrict__ x,
                                                const float* __restrict__ th,
                                                u16* __restrict__ Yh,
                                                u16* __restrict__ Yl) {
    __shared__ float xs[64][65];   // [v][k]
    __shared__ float ts[64][65];   // [k][c]
    const int t = threadIdx.x;
    const int n  = blockIdx.x >> 6;
    const int v0 = (blockIdx.x & 63) * 64;

#pragma unroll
    for (int i = 0; i < 4; ++i) {
        const int idx = i * 256 + t;
        const int row = idx >> 4, q = (idx & 15) * 4;
        const float4 xv = *(const float4*)&x[((size_t)(n * NV + v0 + row)) * 64 + q];
        const float4 tv = *(const float4*)&th[(size_t)row * 64 + q];
        xs[row][q] = xv.x; xs[row][q + 1] = xv.y; xs[row][q + 2] = xv.z; xs[row][q + 3] = xv.w;
        ts[row][q] = tv.x; ts[row][q + 1] = tv.y; ts[row][q + 2] = tv.z; ts[row][q + 3] = tv.w;
    }
    __syncthreads();

    const int v4 = (t & 15) * 4;
    const int c4 = (t >> 4) * 4;
    float acc[4][4] = {};   // [c][v]
#pragma unroll
    for (int k = 0; k < 64; ++k) {
        float tv[4], xv[4];
#pragma unroll
        for (int i = 0; i < 4; ++i) { tv[i] = ts[k][c4 + i]; xv[i] = xs[v4 + i][k]; }
#pragma unroll
        for (int i = 0; i < 4; ++i)
#pragma unroll
            for (int j = 0; j < 4; ++j) acc[i][j] += tv[i] * xv[j];
    }
#pragma unroll
    for (int i = 0; i < 4; ++i) {
        ushort4 hi, lo;
        u16 h;
        h = f2bf_rne(acc[i][0]); hi.x = h; lo.x = f2bf_rne(acc[i][0] - bf2f(h));
        h = f2bf_rne(acc[i][1]); hi.y = h; lo.y = f2bf_rne(acc[i][1] - bf2f(h));
        h = f2bf_rne(acc[i][2]); hi.z = h; lo.z = f2bf_rne(acc[i][2] - bf2f(h));
        h = f2bf_rne(acc[i][3]); hi.w = h; lo.w = f2bf_rne(acc[i][3] - bf2f(h));
        const size_t o = ((size_t)n * 64 + c4 + i) * NV + v0 + v4;
        *(ushort4*)&Yh[o] = hi;
        *(ushort4*)&Yl[o] = lo;
    }
}

// ---------------------------------------------------------------------------
// Kernel 2: vertex->edge MFMA partials. No LDS, no barriers, free-running.
//   P2[sp][n][c][e] = sum_{v in Krange} H[n,v,e]*(Yh+Yl)[n,v,c]
// Block: e-tile 64, all 64 c. Wave w = c-block w (16 c). Per wave per step:
// 4 A bit-words (L2) + 2 B 16B loads (L2) + 8 MFMA.
// ---------------------------------------------------------------------------
__global__ __launch_bounds__(256) void k_v2e(const uint32_t* __restrict__ HT,
                                             const u16* __restrict__ Yh,
                                             const u16* __restrict__ Yl,
                                             float* __restrict__ P2) {
    const int n  = blockIdx.z;
    const int sp = blockIdx.y;
    const int e0 = blockIdx.x * 64;
    const int krange = NV / gridDim.y;
    const int kk0 = sp * krange;
    const int S   = krange / 32;

    const int t = threadIdx.x, w = t >> 6, l = t & 63;
    const int lq = l >> 4, lr = l & 15;
    const int sh = lq * 8;

    const uint32_t* __restrict__ ht =
        HT + ((size_t)n * (NE / 16) + (e0 >> 4)) * ((NV / 32) * 16) + (kk0 >> 5) * 16 + lr;
    const u16* __restrict__ ybh = Yh + ((size_t)n * 64 + w * 16 + lr) * NV + kk0 + lq * 8;
    const u16* __restrict__ ybl = Yl + ((size_t)n * 64 + w * 16 + lr) * NV + kk0 + lq * 8;

    f32x4 acc0 = {0.f,0.f,0.f,0.f}, acc1 = acc0, acc2 = acc0, acc3 = acc0;

#pragma unroll 2
    for (int s = 0; s < S; ++s) {
        const u16x8 bh = *(const u16x8*)(ybh + s * 32);
        const u16x8 bl = *(const u16x8*)(ybl + s * 32);
        const uint32_t w0 = ht[0 * ((NV / 32) * 16) + s * 16];
        const uint32_t w1 = ht[1 * ((NV / 32) * 16) + s * 16];
        const uint32_t w2 = ht[2 * ((NV / 32) * 16) + s * 16];
        const uint32_t w3 = ht[3 * ((NV / 32) * 16) + s * 16];
        u16x8 a;
        a = expand8((w0 >> sh) & 0xFF);
        acc0 = mfma_bf16(a, bh, acc0); acc0 = mfma_bf16(a, bl, acc0);
        a = expand8((w1 >> sh) & 0xFF);
        acc1 = mfma_bf16(a, bh, acc1); acc1 = mfma_bf16(a, bl, acc1);
        a = expand8((w2 >> sh) & 0xFF);
        acc2 = mfma_bf16(a, bh, acc2); acc2 = mfma_bf16(a, bl, acc2);
        a = expand8((w3 >> sh) & 0xFF);
        acc3 = mfma_bf16(a, bh, acc3); acc3 = mfma_bf16(a, bl, acc3);
    }

    // D: row e = e0 + eb*16 + lq*4 + reg, col c = w*16 + lr
    float* pb = P2 + (((size_t)sp * N_B + n) * 64 + w * 16 + lr) * NE + e0 + lq * 4;
    *(f32x4*)(pb + 0)  = acc0;
    *(f32x4*)(pb + 16) = acc1;
    *(f32x4*)(pb + 32) = acc2;
    *(f32x4*)(pb + 48) = acc3;
}

// ---------------------------------------------------------------------------
// Kernel 3: Z_{h,l}[n][c][e] = bf16 hi/lo of (sum_sp P2)/de
// ---------------------------------------------------------------------------
__global__ __launch_bounds__(256) void k_red2(const float* __restrict__ P2,
                                              const float* __restrict__ de,
                                              u16* __restrict__ Zh,
                                              u16* __restrict__ Zl, int nsp) {
    const int i = blockIdx.x * 256 + threadIdx.x;   // 0..131071
    const int row = i >> 9;                          // n*64 + c
    const int e4  = (i & 511) * 4;
    const int n   = row >> 6;

    float4 a = make_float4(0.f, 0.f, 0.f, 0.f);
    for (int sp = 0; sp < nsp; ++sp) {
        const float4 p = *(const float4*)&P2[((size_t)sp * 256 + row) * NE + e4];
        a.x += p.x; a.y += p.y; a.z += p.z; a.w += p.w;
    }
    const float4 d = *(const float4*)&de[(size_t)n * NE + e4];
    float z[4] = {a.x / d.x, a.y / d.y, a.z / d.z, a.w / d.w};
    ushort4 hi, lo;
    u16 h;
    h = f2bf_rne(z[0]); hi.x = h; lo.x = f2bf_rne(z[0] - bf2f(h));
    h = f2bf_rne(z[1]); hi.y = h; lo.y = f2bf_rne(z[1] - bf2f(h));
    h = f2bf_rne(z[2]); hi.z = h; lo.z = f2bf_rne(z[2] - bf2f(h));
    h = f2bf_rne(z[3]); hi.w = h; lo.w = f2bf_rne(z[3] - bf2f(h));
    *(ushort4*)&Zh[(size_t)row * NE + e4] = hi;
    *(ushort4*)&Zl[(size_t)row * NE + e4] = lo;
}

// ---------------------------------------------------------------------------
// Kernel 4: edge->vertex MFMA partials. No LDS, no barriers.
//   P3[sp][n][c][v] = sum_{e in Krange} H[n,v,e]*(Zh+Zl)[n,e,c]
// ---------------------------------------------------------------------------
__global__ __launch_bounds__(256) void k_e2v(const uint32_t* __restrict__ HB,
                                             const u16* __restrict__ Zh,
                                             const u16* __restrict__ Zl,
                                             float* __restrict__ P3) {
    const int n  = blockIdx.z;
    const int sp = blockIdx.y;
    const int v0 = blockIdx.x * 64;
    const int krange = NE / gridDim.y;
    const int kk0 = sp * krange;
    const int S   = krange / 32;

    const int t = threadIdx.x, w = t >> 6, l = t & 63;
    const int lq = l >> 4, lr = l & 15;
    const int sh = lq * 8;

    const uint32_t* __restrict__ hb =
        HB + ((size_t)n * (NV / 16) + (v0 >> 4)) * ((NE / 32) * 16) + (kk0 >> 5) * 16 + lr;
    const u16* __restrict__ zbh = Zh + ((size_t)n * 64 + w * 16 + lr) * NE + kk0 + lq * 8;
    const u16* __restrict__ zbl = Zl + ((size_t)n * 64 + w * 16 + lr) * NE + kk0 + lq * 8;

    f32x4 acc0 = {0.f,0.f,0.f,0.f}, acc1 = acc0, acc2 = acc0, acc3 = acc0;

#pragma unroll 2
    for (int s = 0; s < S; ++s) {
        const u16x8 bh = *(const u16x8*)(zbh + s * 32);
        const u16x8 bl = *(const u16x8*)(zbl + s * 32);
        const uint32_t w0 = hb[0 * ((NE / 32) * 16) + s * 16];
        const uint32_t w1 = hb[1 * ((NE / 32) * 16) + s * 16];
        const uint32_t w2 = hb[2 * ((NE / 32) * 16) + s * 16];
        const uint32_t w3 = hb[3 * ((NE / 32) * 16) + s * 16];
        u16x8 a;
        a = expand8((w0 >> sh) & 0xFF);
        acc0 = mfma_bf16(a, bh, acc0); acc0 = mfma_bf16(a, bl, acc0);
        a = expand8((w1 >> sh) & 0xFF);
        acc1 = mfma_bf16(a, bh, acc1); acc1 = mfma_bf16(a, bl, acc1);
        a = expand8((w2 >> sh) & 0xFF);
        acc2 = mfma_bf16(a, bh, acc2); acc2 = mfma_bf16(a, bl, acc2);
        a = expand8((w3 >> sh) & 0xFF);
        acc3 = mfma_bf16(a, bh, acc3); acc3 = mfma_bf16(a, bl, acc3);
    }

    // D: row v = v0 + vb*16 + lq*4 + reg, col c = w*16 + lr
    float* pb = P3 + (((size_t)sp * N_B + n) * 64 + w * 16 + lr) * NV + v0 + lq * 4;
    *(f32x4*)(pb + 0)  = acc0;
    *(f32x4*)(pb + 16) = acc1;
    *(f32x4*)(pb + 32) = acc2;
    *(f32x4*)(pb + 48) = acc3;
}

// ---------------------------------------------------------------------------
// Kernel 5: out[n][v][c] = (sum_sp P3[sp][n][c][v]) / dv + bias  (transpose)
// ---------------------------------------------------------------------------
__global__ __launch_bounds__(512) void k_red3(const float* __restrict__ P3,
                                              const float* __restrict__ dv,
                                              const float* __restrict__ bias,
                                              float* __restrict__ out, int nsp) {
    __shared__ float lt[64][68];
    const int n  = blockIdx.y;
    const int v0 = blockIdx.x * 64;
    const int t  = threadIdx.x;

    {
        const int c   = t >> 3;
        const int vch = (t & 7) * 8;
        float4 s0 = make_float4(0.f, 0.f, 0.f, 0.f), s1 = s0;
        for (int sp = 0; sp < nsp; ++sp) {
            const size_t base = (((size_t)sp * N_B + n) * 64 + c) * NV + v0 + vch;
            const float4 p0 = *(const float4*)&P3[base];
            const float4 p1 = *(const float4*)&P3[base + 4];
            s0.x += p0.x; s0.y += p0.y; s0.z += p0.z; s0.w += p0.w;
            s1.x += p1.x; s1.y += p1.y; s1.z += p1.z; s1.w += p1.w;
        }
        *(float4*)&lt[c][vch]     = s0;
        *(float4*)&lt[c][vch + 4] = s1;
    }
    const int vw  = t >> 3;
    const int cch = (t & 7) * 8;
    const float dsum = dv[(size_t)n * NV + v0 + vw];
    __syncthreads();

    const float rdv = 1.0f / dsum;
    const float4 b0 = *(const float4*)&bias[cch];
    const float4 b1 = *(const float4*)&bias[cch + 4];
    float4 o0, o1;
    o0.x = lt[cch + 0][vw] * rdv + b0.x;
    o0.y = lt[cch + 1][vw] * rdv + b0.y;
    o0.z = lt[cch + 2][vw] * rdv + b0.z;
    o0.w = lt[cch + 3][vw] * rdv + b0.w;
    o1.x = lt[cch + 4][vw] * rdv + b1.x;
    o1.y = lt[cch + 5][vw] * rdv + b1.y;
    o1.z = lt[cch + 6][vw] * rdv + b1.z;
    o1.w = lt[cch + 7][vw] * rdv + b1.w;
    float* dst = out + ((size_t)n * NV + v0 + vw) * 64 + cch;
    *(float4*)dst       = o0;
    *(float4*)(dst + 4) = o1;
}

// ---------------------------------------------------------------------------
extern "C" void kernel_launch(void* const* d_in, const int* in_sizes, int n_in,
                              void* d_out, int out_size, void* d_ws, size_t ws_size,
                              hipStream_t stream) {
    const float* x     = (const float*)d_in[0];
    const float* H     = (const float*)d_in[1];
    const float* theta = (const float*)d_in[2];
    const float* bias  = (const float*)d_in[3];
    float* out = (float*)d_out;

    const size_t yE   = (size_t)N_B * 64 * NV;        // 1,048,576
    const size_t zE   = (size_t)N_B * 64 * NE;        //   524,288
    const size_t HBW  = (size_t)N_B * (NV / 16) * (NE / 32) * 16;   // 1,048,576 u32
    const size_t HTW  = (size_t)N_B * (NE / 16) * (NV / 32) * 16;   // 1,048,576 u32
    const size_t depE = (size_t)64 * N_B * NE;        //   524,288
    const size_t dvpE = (size_t)32 * N_B * NV;        //   524,288
    const size_t deE  = (size_t)N_B * NE;             //     8,192
    const size_t dvE  = (size_t)N_B * NV;             //    16,384

    u16* Yh = (u16*)d_ws;
    u16* Yl = Yh + yE;
    u16* Zh = Yl + yE;
    u16* Zl = Zh + zE;
    uint32_t* HB = (uint32_t*)(Zl + zE);
    uint32_t* HT = HB + HBW;
    float* deP = (float*)(HT + HTW);
    float* dvP = deP + depE;
    float* de  = dvP + dvpE;
    float* dv  = de + deE;
    float* fbase = dv + dvE;

    const size_t fixed_bytes = (size_t)((char*)fbase - (char*)d_ws);
    const size_t avail_f = (ws_size > fixed_bytes) ? (ws_size - fixed_bytes) / 4 : 0;

    const size_t unit2 = zE;   // P2 per split (floats)
    const size_t unit3 = yE;   // P3 per split (floats)
    int s2 = 1, s3 = 1;
    if      (avail_f >= 16 * unit2 + 8 * unit3) { s2 = 16; s3 = 8; }
    else if (avail_f >=  8 * unit2 + 4 * unit3) { s2 = 8;  s3 = 4; }
    else if (avail_f >=  4 * unit2 + 2 * unit3) { s2 = 4;  s3 = 2; }
    else if (avail_f >=  2 * unit2 + 1 * unit3) { s2 = 2;  s3 = 1; }

    float* P2 = fbase;
    float* P3 = P2 + (size_t)s2 * zE;

    k_pack<<<dim3(NE / 64, NV / 64, N_B), 256, 0, stream>>>(H, HB, HT, dvP, deP);
    k_xtheta<<<dim3(N_B * NV / 64), 256, 0, stream>>>(x, theta, Yh, Yl);
    k_deg<<<dim3((N_B * NE + N_B * NV) / 256), 256, 0, stream>>>(dvP, deP, dv, de);
    k_v2e<<<dim3(NE / 64, s2, N_B), 256, 0, stream>>>(HT, Yh, Yl, P2);
    k_red2<<<dim3((int)(zE / 4 / 256)), 256, 0, stream>>>(P2, de, Zh, Zl, s2);
    k_e2v<<<dim3(NV / 64, s3, N_B), 256, 0, stream>>>(HB, Zh, Zl, P3);
    k_red3<<<dim3(NV / 64, N_B), 512, 0, stream>>>(P3, dv, bias, out, s3);
}

// Round 8
// 113.643 us; speedup vs baseline: 1.6453x; 1.0580x over previous
//
#include <hip/hip_runtime.h>
#include <hip/hip_bf16.h>
#include <stdint.h>

#define N_B 4
#define NV 4096
#define NE 2048
#define NC 64

typedef float    f32x4  __attribute__((ext_vector_type(4)));
typedef __bf16   bf16x8 __attribute__((ext_vector_type(8)));
typedef unsigned short u16;
typedef u16      u16x8  __attribute__((ext_vector_type(8)));
typedef uint32_t u32x4  __attribute__((ext_vector_type(4)));

__device__ __forceinline__ u16 f2bf_rne(float f) {
    uint32_t u = __builtin_bit_cast(uint32_t, f);
    u += 0x7FFFu + ((u >> 16) & 1u);
    return (u16)(u >> 16);
}
__device__ __forceinline__ float bf2f(u16 h) {
    uint32_t u = ((uint32_t)h) << 16;
    return __builtin_bit_cast(float, u);
}
__device__ __forceinline__ f32x4 mfma_bf16(u16x8 a, u16x8 b, f32x4 c) {
    return __builtin_amdgcn_mfma_f32_16x16x32_bf16(
        __builtin_bit_cast(bf16x8, a), __builtin_bit_cast(bf16x8, b), c, 0, 0, 0);
}
// 8 bits -> 8 bf16 (1.0/0.0). u16 lane j = bit j.
__device__ __forceinline__ u16x8 expand8(uint32_t byte) {
    u32x4 w;
#pragma unroll
    for (int p = 0; p < 4; ++p) {
        const uint32_t lo = (byte >> (2 * p)) & 1u;
        const uint32_t hi = (byte >> (2 * p + 1)) & 1u;
        w[p] = (lo | (hi << 16)) * 0x3F80u;
    }
    return __builtin_bit_cast(u16x8, w);
}

// ---------------------------------------------------------------------------
// Kernel P: pack H (fp32 0/1) into bitmasks, both orientations, + degree
// partials via popcount.  (unchanged from round 7)
// ---------------------------------------------------------------------------
__global__ __launch_bounds__(256) void k_pack(const float* __restrict__ H,
                                              uint32_t* __restrict__ HB,
                                              uint32_t* __restrict__ HT,
                                              float* __restrict__ dvP,
                                              float* __restrict__ deP) {
    __shared__ float tile[64][65];
    const int n  = blockIdx.z;
    const int v0 = blockIdx.y * 64;
    const int e0 = blockIdx.x * 64;
    const int t = threadIdx.x, w = t >> 6, l = t & 63;

    const float* __restrict__ Hn = H + ((size_t)n * NV + v0) * NE + e0;

#pragma unroll 4
    for (int i = 0; i < 16; ++i) {
        const int row = w * 16 + i;
        const float h = Hn[(size_t)row * NE + l];
        tile[row][l] = h;
        const unsigned long long m = __ballot(h != 0.0f);
        if (l == 0)
            dvP[((size_t)blockIdx.x * N_B + n) * NV + v0 + row] = (float)__popcll(m);
        if (l < 2)
            HB[(((size_t)n * (NV / 16) + ((v0 + row) >> 4)) * (NE / 32) + (e0 >> 5) + l) * 16 +
               ((v0 + row) & 15)] = (uint32_t)(m >> (32 * l));
    }
    __syncthreads();

#pragma unroll 4
    for (int i = 0; i < 16; ++i) {
        const int col = w * 16 + i;
        const float h = tile[l][col];
        const unsigned long long m = __ballot(h != 0.0f);
        if (l == 0)
            deP[((size_t)blockIdx.y * N_B + n) * NE + e0 + col] = (float)__popcll(m);
        if (l < 2)
            HT[(((size_t)n * (NE / 16) + ((e0 + col) >> 4)) * (NV / 32) + (v0 >> 5) + l) * 16 +
               ((e0 + col) & 15)] = (uint32_t)(m >> (32 * l));
    }
}

// ---------------------------------------------------------------------------
// Kernel D: collapse degree partials.
// ---------------------------------------------------------------------------
__global__ __launch_bounds__(256) void k_deg(const float* __restrict__ dvP,
                                             const float* __restrict__ deP,
                                             float* __restrict__ dv,
                                             float* __restrict__ de) {
    const int id = blockIdx.x * 256 + threadIdx.x;
    if (id < N_B * NE) {
        float s = 0.f;
        for (int vt = 0; vt < 64; ++vt) s += deP[(size_t)vt * (N_B * NE) + id];
        de[id] = s;
    } else {
        const int j = id - N_B * NE;
        float s = 0.f;
        for (int et = 0; et < 32; ++et) s += dvP[(size_t)et * (N_B * NV) + j];
        dv[j] = s;
    }
}

// ---------------------------------------------------------------------------
// Kernel 1: Yht_{h,l}[n][c][v] (bf16 hi/lo) = transpose of x@theta.
// ---------------------------------------------------------------------------
__global__ __launch_bounds__(256) void k_xtheta(const float* __restrict__ x,
                                                const float* __restrict__ th,
                                                u16* __restrict__ Yh,
                                                u16* __restrict__ Yl) {
    __shared__ float xs[64][65];   // [v][k]
    __shared__ float ts[64][65];   // [k][c]
    const int t = threadIdx.x;
    const int n  = blockIdx.x >> 6;
    const int v0 = (blockIdx.x & 63) * 64;

#pragma unroll
    for (int i = 0; i < 4; ++i) {
        const int idx = i * 256 + t;
        const int row = idx >> 4, q = (idx & 15) * 4;
        const float4 xv = *(const float4*)&x[((size_t)(n * NV + v0 + row)) * 64 + q];
        const float4 tv = *(const float4*)&th[(size_t)row * 64 + q];
        xs[row][q] = xv.x; xs[row][q + 1] = xv.y; xs[row][q + 2] = xv.z; xs[row][q + 3] = xv.w;
        ts[row][q] = tv.x; ts[row][q + 1] = tv.y; ts[row][q + 2] = tv.z; ts[row][q + 3] = tv.w;
    }
    __syncthreads();

    const int v4 = (t & 15) * 4;
    const int c4 = (t >> 4) * 4;
    float acc[4][4] = {};   // [c][v]
#pragma unroll
    for (int k = 0; k < 64; ++k) {
        float tv[4], xv[4];
#pragma unroll
        for (int i = 0; i < 4; ++i) { tv[i] = ts[k][c4 + i]; xv[i] = xs[v4 + i][k]; }
#pragma unroll
        for (int i = 0; i < 4; ++i)
#pragma unroll
            for (int j = 0; j < 4; ++j) acc[i][j] += tv[i] * xv[j];
    }
#pragma unroll
    for (int i = 0; i < 4; ++i) {
        ushort4 hi, lo;
        u16 h;
        h = f2bf_rne(acc[i][0]); hi.x = h; lo.x = f2bf_rne(acc[i][0] - bf2f(h));
        h = f2bf_rne(acc[i][1]); hi.y = h; lo.y = f2bf_rne(acc[i][1] - bf2f(h));
        h = f2bf_rne(acc[i][2]); hi.z = h; lo.z = f2bf_rne(acc[i][2] - bf2f(h));
        h = f2bf_rne(acc[i][3]); hi.w = h; lo.w = f2bf_rne(acc[i][3] - bf2f(h));
        const size_t o = ((size_t)n * 64 + c4 + i) * NV + v0 + v4;
        *(ushort4*)&Yh[o] = hi;
        *(ushort4*)&Yl[o] = lo;
    }
}

// ---------------------------------------------------------------------------
// Kernel 2: vertex->edge MFMA partials. No LDS, no barriers.
// Explicit depth-1 register prefetch: step s+1's 4 A-words + 2 B-frags are
// loaded BEFORE step s's MFMA cluster; waitcnt for them lands at the next
// iteration's expand -> one full MFMA phase of latency hiding.
// ---------------------------------------------------------------------------
__global__ __launch_bounds__(256, 8) void k_v2e(const uint32_t* __restrict__ HT,
                                                const u16* __restrict__ Yh,
                                                const u16* __restrict__ Yl,
                                                float* __restrict__ P2) {
    const int n  = blockIdx.z;
    const int sp = blockIdx.y;
    const int e0 = blockIdx.x * 64;
    const int krange = NV / gridDim.y;
    const int kk0 = sp * krange;
    const int S   = krange / 32;

    const int t = threadIdx.x, w = t >> 6, l = t & 63;
    const int lq = l >> 4, lr = l & 15;
    const int sh = lq * 8;
    const int hstride = (NV / 32) * 16;

    const uint32_t* __restrict__ ht =
        HT + ((size_t)n * (NE / 16) + (e0 >> 4)) * hstride + (kk0 >> 5) * 16 + lr;
    const u16* __restrict__ ybh = Yh + ((size_t)n * 64 + w * 16 + lr) * NV + kk0 + lq * 8;
    const u16* __restrict__ ybl = Yl + ((size_t)n * 64 + w * 16 + lr) * NV + kk0 + lq * 8;

    f32x4 acc0 = {0.f,0.f,0.f,0.f}, acc1 = acc0, acc2 = acc0, acc3 = acc0;

    // prologue: step-0 operands
    u16x8 bh = *(const u16x8*)ybh;
    u16x8 bl = *(const u16x8*)ybl;
    uint32_t w0 = ht[0 * hstride];
    uint32_t w1 = ht[1 * hstride];
    uint32_t w2 = ht[2 * hstride];
    uint32_t w3 = ht[3 * hstride];

#pragma unroll 2
    for (int s = 0; s < S - 1; ++s) {
        // prefetch step s+1 (independent of MFMAs below)
        const u16x8 bhn = *(const u16x8*)(ybh + (s + 1) * 32);
        const u16x8 bln = *(const u16x8*)(ybl + (s + 1) * 32);
        const uint32_t w0n = ht[0 * hstride + (s + 1) * 16];
        const uint32_t w1n = ht[1 * hstride + (s + 1) * 16];
        const uint32_t w2n = ht[2 * hstride + (s + 1) * 16];
        const uint32_t w3n = ht[3 * hstride + (s + 1) * 16];

        u16x8 a;
        a = expand8((w0 >> sh) & 0xFF);
        acc0 = mfma_bf16(a, bh, acc0); acc0 = mfma_bf16(a, bl, acc0);
        a = expand8((w1 >> sh) & 0xFF);
        acc1 = mfma_bf16(a, bh, acc1); acc1 = mfma_bf16(a, bl, acc1);
        a = expand8((w2 >> sh) & 0xFF);
        acc2 = mfma_bf16(a, bh, acc2); acc2 = mfma_bf16(a, bl, acc2);
        a = expand8((w3 >> sh) & 0xFF);
        acc3 = mfma_bf16(a, bh, acc3); acc3 = mfma_bf16(a, bl, acc3);

        bh = bhn; bl = bln; w0 = w0n; w1 = w1n; w2 = w2n; w3 = w3n;
    }
    {   // epilogue: last step, no prefetch
        u16x8 a;
        a = expand8((w0 >> sh) & 0xFF);
        acc0 = mfma_bf16(a, bh, acc0); acc0 = mfma_bf16(a, bl, acc0);
        a = expand8((w1 >> sh) & 0xFF);
        acc1 = mfma_bf16(a, bh, acc1); acc1 = mfma_bf16(a, bl, acc1);
        a = expand8((w2 >> sh) & 0xFF);
        acc2 = mfma_bf16(a, bh, acc2); acc2 = mfma_bf16(a, bl, acc2);
        a = expand8((w3 >> sh) & 0xFF);
        acc3 = mfma_bf16(a, bh, acc3); acc3 = mfma_bf16(a, bl, acc3);
    }

    // D: row e = e0 + eb*16 + lq*4 + reg, col c = w*16 + lr
    float* pb = P2 + (((size_t)sp * N_B + n) * 64 + w * 16 + lr) * NE + e0 + lq * 4;
    *(f32x4*)(pb + 0)  = acc0;
    *(f32x4*)(pb + 16) = acc1;
    *(f32x4*)(pb + 32) = acc2;
    *(f32x4*)(pb + 48) = acc3;
}

// ---------------------------------------------------------------------------
// Kernel 3: Z_{h,l}[n][c][e] = bf16 hi/lo of (sum_sp P2)/de
// ---------------------------------------------------------------------------
__global__ __launch_bounds__(256) void k_red2(const float* __restrict__ P2,
                                              const float* __restrict__ de,
                                              u16* __restrict__ Zh,
                                              u16* __restrict__ Zl, int nsp) {
    const int i = blockIdx.x * 256 + threadIdx.x;   // 0..131071
    const int row = i >> 9;                          // n*64 + c
    const int e4  = (i & 511) * 4;
    const int n   = row >> 6;

    float4 a = make_float4(0.f, 0.f, 0.f, 0.f);
    for (int sp = 0; sp < nsp; ++sp) {
        const float4 p = *(const float4*)&P2[((size_t)sp * 256 + row) * NE + e4];
        a.x += p.x; a.y += p.y; a.z += p.z; a.w += p.w;
    }
    const float4 d = *(const float4*)&de[(size_t)n * NE + e4];
    float z[4] = {a.x / d.x, a.y / d.y, a.z / d.z, a.w / d.w};
    ushort4 hi, lo;
    u16 h;
    h = f2bf_rne(z[0]); hi.x = h; lo.x = f2bf_rne(z[0] - bf2f(h));
    h = f2bf_rne(z[1]); hi.y = h; lo.y = f2bf_rne(z[1] - bf2f(h));
    h = f2bf_rne(z[2]); hi.z = h; lo.z = f2bf_rne(z[2] - bf2f(h));
    h = f2bf_rne(z[3]); hi.w = h; lo.w = f2bf_rne(z[3] - bf2f(h));
    *(ushort4*)&Zh[(size_t)row * NE + e4] = hi;
    *(ushort4*)&Zl[(size_t)row * NE + e4] = lo;
}

// ---------------------------------------------------------------------------
// Kernel 4: edge->vertex MFMA partials. No LDS, no barriers, depth-1 prefetch.
// ---------------------------------------------------------------------------
__global__ __launch_bounds__(256, 8) void k_e2v(const uint32_t* __restrict__ HB,
                                                const u16* __restrict__ Zh,
                                                const u16* __restrict__ Zl,
                                                float* __restrict__ P3) {
    const int n  = blockIdx.z;
    const int sp = blockIdx.y;
    const int v0 = blockIdx.x * 64;
    const int krange = NE / gridDim.y;
    const int kk0 = sp * krange;
    const int S   = krange / 32;

    const int t = threadIdx.x, w = t >> 6, l = t & 63;
    const int lq = l >> 4, lr = l & 15;
    const int sh = lq * 8;
    const int estride = (NE / 32) * 16;

    const uint32_t* __restrict__ hb =
        HB + ((size_t)n * (NV / 16) + (v0 >> 4)) * estride + (kk0 >> 5) * 16 + lr;
    const u16* __restrict__ zbh = Zh + ((size_t)n * 64 + w * 16 + lr) * NE + kk0 + lq * 8;
    const u16* __restrict__ zbl = Zl + ((size_t)n * 64 + w * 16 + lr) * NE + kk0 + lq * 8;

    f32x4 acc0 = {0.f,0.f,0.f,0.f}, acc1 = acc0, acc2 = acc0, acc3 = acc0;

    u16x8 bh = *(const u16x8*)zbh;
    u16x8 bl = *(const u16x8*)zbl;
    uint32_t w0 = hb[0 * estride];
    uint32_t w1 = hb[1 * estride];
    uint32_t w2 = hb[2 * estride];
    uint32_t w3 = hb[3 * estride];

#pragma unroll 2
    for (int s = 0; s < S - 1; ++s) {
        const u16x8 bhn = *(const u16x8*)(zbh + (s + 1) * 32);
        const u16x8 bln = *(const u16x8*)(zbl + (s + 1) * 32);
        const uint32_t w0n = hb[0 * estride + (s + 1) * 16];
        const uint32_t w1n = hb[1 * estride + (s + 1) * 16];
        const uint32_t w2n = hb[2 * estride + (s + 1) * 16];
        const uint32_t w3n = hb[3 * estride + (s + 1) * 16];

        u16x8 a;
        a = expand8((w0 >> sh) & 0xFF);
        acc0 = mfma_bf16(a, bh, acc0); acc0 = mfma_bf16(a, bl, acc0);
        a = expand8((w1 >> sh) & 0xFF);
        acc1 = mfma_bf16(a, bh, acc1); acc1 = mfma_bf16(a, bl, acc1);
        a = expand8((w2 >> sh) & 0xFF);
        acc2 = mfma_bf16(a, bh, acc2); acc2 = mfma_bf16(a, bl, acc2);
        a = expand8((w3 >> sh) & 0xFF);
        acc3 = mfma_bf16(a, bh, acc3); acc3 = mfma_bf16(a, bl, acc3);

        bh = bhn; bl = bln; w0 = w0n; w1 = w1n; w2 = w2n; w3 = w3n;
    }
    {
        u16x8 a;
        a = expand8((w0 >> sh) & 0xFF);
        acc0 = mfma_bf16(a, bh, acc0); acc0 = mfma_bf16(a, bl, acc0);
        a = expand8((w1 >> sh) & 0xFF);
        acc1 = mfma_bf16(a, bh, acc1); acc1 = mfma_bf16(a, bl, acc1);
        a = expand8((w2 >> sh) & 0xFF);
        acc2 = mfma_bf16(a, bh, acc2); acc2 = mfma_bf16(a, bl, acc2);
        a = expand8((w3 >> sh) & 0xFF);
        acc3 = mfma_bf16(a, bh, acc3); acc3 = mfma_bf16(a, bl, acc3);
    }

    float* pb = P3 + (((size_t)sp * N_B + n) * 64 + w * 16 + lr) * NV + v0 + lq * 4;
    *(f32x4*)(pb + 0)  = acc0;
    *(f32x4*)(pb + 16) = acc1;
    *(f32x4*)(pb + 32) = acc2;
    *(f32x4*)(pb + 48) = acc3;
}

// ---------------------------------------------------------------------------
// Kernel 5: out[n][v][c] = (sum_sp P3[sp][n][c][v]) / dv + bias  (transpose)
// ---------------------------------------------------------------------------
__global__ __launch_bounds__(512) void k_red3(const float* __restrict__ P3,
                                              const float* __restrict__ dv,
                                              const float* __restrict__ bias,
                                              float* __restrict__ out, int nsp) {
    __shared__ float lt[64][68];
    const int n  = blockIdx.y;
    const int v0 = blockIdx.x * 64;
    const int t  = threadIdx.x;

    {
        const int c   = t >> 3;
        const int vch = (t & 7) * 8;
        float4 s0 = make_float4(0.f, 0.f, 0.f, 0.f), s1 = s0;
        for (int sp = 0; sp < nsp; ++sp) {
            const size_t base = (((size_t)sp * N_B + n) * 64 + c) * NV + v0 + vch;
            const float4 p0 = *(const float4*)&P3[base];
            const float4 p1 = *(const float4*)&P3[base + 4];
            s0.x += p0.x; s0.y += p0.y; s0.z += p0.z; s0.w += p0.w;
            s1.x += p1.x; s1.y += p1.y; s1.z += p1.z; s1.w += p1.w;
        }
        *(float4*)&lt[c][vch]     = s0;
        *(float4*)&lt[c][vch + 4] = s1;
    }
    const int vw  = t >> 3;
    const int cch = (t & 7) * 8;
    const float dsum = dv[(size_t)n * NV + v0 + vw];
    __syncthreads();

    const float rdv = 1.0f / dsum;
    const float4 b0 = *(const float4*)&bias[cch];
    const float4 b1 = *(const float4*)&bias[cch + 4];
    float4 o0, o1;
    o0.x = lt[cch + 0][vw] * rdv + b0.x;
    o0.y = lt[cch + 1][vw] * rdv + b0.y;
    o0.z = lt[cch + 2][vw] * rdv + b0.z;
    o0.w = lt[cch + 3][vw] * rdv + b0.w;
    o1.x = lt[cch + 4][vw] * rdv + b1.x;
    o1.y = lt[cch + 5][vw] * rdv + b1.y;
    o1.z = lt[cch + 6][vw] * rdv + b1.z;
    o1.w = lt[cch + 7][vw] * rdv + b1.w;
    float* dst = out + ((size_t)n * NV + v0 + vw) * 64 + cch;
    *(float4*)dst       = o0;
    *(float4*)(dst + 4) = o1;
}

// ---------------------------------------------------------------------------
extern "C" void kernel_launch(void* const* d_in, const int* in_sizes, int n_in,
                              void* d_out, int out_size, void* d_ws, size_t ws_size,
                              hipStream_t stream) {
    const float* x     = (const float*)d_in[0];
    const float* H     = (const float*)d_in[1];
    const float* theta = (const float*)d_in[2];
    const float* bias  = (const float*)d_in[3];
    float* out = (float*)d_out;

    const size_t yE   = (size_t)N_B * 64 * NV;
    const size_t zE   = (size_t)N_B * 64 * NE;
    const size_t HBW  = (size_t)N_B * (NV / 16) * (NE / 32) * 16;
    const size_t HTW  = (size_t)N_B * (NE / 16) * (NV / 32) * 16;
    const size_t depE = (size_t)64 * N_B * NE;
    const size_t dvpE = (size_t)32 * N_B * NV;
    const size_t deE  = (size_t)N_B * NE;
    const size_t dvE  = (size_t)N_B * NV;

    u16* Yh = (u16*)d_ws;
    u16* Yl = Yh + yE;
    u16* Zh = Yl + yE;
    u16* Zl = Zh + zE;
    uint32_t* HB = (uint32_t*)(Zl + zE);
    uint32_t* HT = HB + HBW;
    float* deP = (float*)(HT + HTW);
    float* dvP = deP + depE;
    float* de  = dvP + dvpE;
    float* dv  = de + deE;
    float* fbase = dv + dvE;

    const size_t fixed_bytes = (size_t)((char*)fbase - (char*)d_ws);
    const size_t avail_f = (ws_size > fixed_bytes) ? (ws_size - fixed_bytes) / 4 : 0;

    const size_t unit2 = zE;
    const size_t unit3 = yE;
    int s2 = 1, s3 = 1;
    if      (avail_f >= 16 * unit2 + 8 * unit3) { s2 = 16; s3 = 8; }
    else if (avail_f >=  8 * unit2 + 4 * unit3) { s2 = 8;  s3 = 4; }
    else if (avail_f >=  4 * unit2 + 2 * unit3) { s2 = 4;  s3 = 2; }
    else if (avail_f >=  2 * unit2 + 1 * unit3) { s2 = 2;  s3 = 1; }

    float* P2 = fbase;
    float* P3 = P2 + (size_t)s2 * zE;

    k_pack<<<dim3(NE / 64, NV / 64, N_B), 256, 0, stream>>>(H, HB, HT, dvP, deP);
    k_xtheta<<<dim3(N_B * NV / 64), 256, 0, stream>>>(x, theta, Yh, Yl);
    k_deg<<<dim3((N_B * NE + N_B * NV) / 256), 256, 0, stream>>>(dvP, deP, dv, de);
    k_v2e<<<dim3(NE / 64, s2, N_B), 256, 0, stream>>>(HT, Yh, Yl, P2);
    k_red2<<<dim3((int)(zE / 4 / 256)), 256, 0, stream>>>(P2, de, Zh, Zl, s2);
    k_e2v<<<dim3(NV / 64, s3, N_B), 256, 0, stream>>>(HB, Zh, Zl, P3);
    k_red3<<<dim3(NV / 64, N_B), 512, 0, stream>>>(P3, dv, bias, out, s3);
}

// Round 9
// 106.445 us; speedup vs baseline: 1.7566x; 1.0676x over previous
//
#include <hip/hip_runtime.h>
#include <hip/hip_bf16.h>
#include <stdint.h>

#define N_B 4
#define NV 4096
#define NE 2048
#define NC 64

typedef float    f32x4  __attribute__((ext_vector_type(4)));
typedef __bf16   bf16x8 __attribute__((ext_vector_type(8)));
typedef unsigned short u16;
typedef u16      u16x8  __attribute__((ext_vector_type(8)));
typedef uint32_t u32x4  __attribute__((ext_vector_type(4)));

__device__ __forceinline__ u16 f2bf_rne(float f) {
    uint32_t u = __builtin_bit_cast(uint32_t, f);
    u += 0x7FFFu + ((u >> 16) & 1u);
    return (u16)(u >> 16);
}
__device__ __forceinline__ float bf2f(u16 h) {
    uint32_t u = ((uint32_t)h) << 16;
    return __builtin_bit_cast(float, u);
}
__device__ __forceinline__ f32x4 mfma_bf16(u16x8 a, u16x8 b, f32x4 c) {
    return __builtin_amdgcn_mfma_f32_16x16x32_bf16(
        __builtin_bit_cast(bf16x8, a), __builtin_bit_cast(bf16x8, b), c, 0, 0, 0);
}
// 8 bits -> 8 bf16 (1.0/0.0). u16 lane j = bit j.
__device__ __forceinline__ u16x8 expand8(uint32_t byte) {
    u32x4 w;
#pragma unroll
    for (int p = 0; p < 4; ++p) {
        const uint32_t lo = (byte >> (2 * p)) & 1u;
        const uint32_t hi = (byte >> (2 * p + 1)) & 1u;
        w[p] = (lo | (hi << 16)) * 0x3F80u;
    }
    return __builtin_bit_cast(u16x8, w);
}

// ---------------------------------------------------------------------------
// Kernel P: pack H (fp32 0/1) into bitmasks, both orientations, + degree
// partials via popcount.
// ---------------------------------------------------------------------------
__global__ __launch_bounds__(256) void k_pack(const float* __restrict__ H,
                                              uint32_t* __restrict__ HB,
                                              uint32_t* __restrict__ HT,
                                              float* __restrict__ dvP,
                                              float* __restrict__ deP) {
    __shared__ float tile[64][65];
    const int n  = blockIdx.z;
    const int v0 = blockIdx.y * 64;
    const int e0 = blockIdx.x * 64;
    const int t = threadIdx.x, w = t >> 6, l = t & 63;

    const float* __restrict__ Hn = H + ((size_t)n * NV + v0) * NE + e0;

#pragma unroll 4
    for (int i = 0; i < 16; ++i) {
        const int row = w * 16 + i;
        const float h = Hn[(size_t)row * NE + l];
        tile[row][l] = h;
        const unsigned long long m = __ballot(h != 0.0f);
        if (l == 0)
            dvP[((size_t)blockIdx.x * N_B + n) * NV + v0 + row] = (float)__popcll(m);
        if (l < 2)
            HB[(((size_t)n * (NV / 16) + ((v0 + row) >> 4)) * (NE / 32) + (e0 >> 5) + l) * 16 +
               ((v0 + row) & 15)] = (uint32_t)(m >> (32 * l));
    }
    __syncthreads();

#pragma unroll 4
    for (int i = 0; i < 16; ++i) {
        const int col = w * 16 + i;
        const float h = tile[l][col];
        const unsigned long long m = __ballot(h != 0.0f);
        if (l == 0)
            deP[((size_t)blockIdx.y * N_B + n) * NE + e0 + col] = (float)__popcll(m);
        if (l < 2)
            HT[(((size_t)n * (NE / 16) + ((e0 + col) >> 4)) * (NV / 32) + (v0 >> 5) + l) * 16 +
               ((e0 + col) & 15)] = (uint32_t)(m >> (32 * l));
    }
}

// ---------------------------------------------------------------------------
// Kernel D: collapse degree partials.
// ---------------------------------------------------------------------------
__global__ __launch_bounds__(256) void k_deg(const float* __restrict__ dvP,
                                             const float* __restrict__ deP,
                                             float* __restrict__ dv,
                                             float* __restrict__ de) {
    const int id = blockIdx.x * 256 + threadIdx.x;
    if (id < N_B * NE) {
        float s = 0.f;
        for (int vt = 0; vt < 64; ++vt) s += deP[(size_t)vt * (N_B * NE) + id];
        de[id] = s;
    } else {
        const int j = id - N_B * NE;
        float s = 0.f;
        for (int et = 0; et < 32; ++et) s += dvP[(size_t)et * (N_B * NV) + j];
        dv[j] = s;
    }
}

// ---------------------------------------------------------------------------
// Kernel 1: Yht_{h,l}[n][c][v] (bf16 hi/lo) = transpose of x@theta.
// ---------------------------------------------------------------------------
__global__ __launch_bounds__(256) void k_xtheta(const float* __restrict__ x,
                                                const float* __restrict__ th,
                                                u16* __restrict__ Yh,
                                                u16* __restrict__ Yl) {
    __shared__ float xs[64][65];   // [v][k]
    __shared__ float ts[64][65];   // [k][c]
    const int t = threadIdx.x;
    const int n  = blockIdx.x >> 6;
    const int v0 = (blockIdx.x & 63) * 64;

#pragma unroll
    for (int i = 0; i < 4; ++i) {
        const int idx = i * 256 + t;
        const int row = idx >> 4, q = (idx & 15) * 4;
        const float4 xv = *(const float4*)&x[((size_t)(n * NV + v0 + row)) * 64 + q];
        const float4 tv = *(const float4*)&th[(size_t)row * 64 + q];
        xs[row][q] = xv.x; xs[row][q + 1] = xv.y; xs[row][q + 2] = xv.z; xs[row][q + 3] = xv.w;
        ts[row][q] = tv.x; ts[row][q + 1] = tv.y; ts[row][q + 2] = tv.z; ts[row][q + 3] = tv.w;
    }
    __syncthreads();

    const int v4 = (t & 15) * 4;
    const int c4 = (t >> 4) * 4;
    float acc[4][4] = {};   // [c][v]
#pragma unroll
    for (int k = 0; k < 64; ++k) {
        float tv[4], xv[4];
#pragma unroll
        for (int i = 0; i < 4; ++i) { tv[i] = ts[k][c4 + i]; xv[i] = xs[v4 + i][k]; }
#pragma unroll
        for (int i = 0; i < 4; ++i)
#pragma unroll
            for (int j = 0; j < 4; ++j) acc[i][j] += tv[i] * xv[j];
    }
#pragma unroll
    for (int i = 0; i < 4; ++i) {
        ushort4 hi, lo;
        u16 h;
        h = f2bf_rne(acc[i][0]); hi.x = h; lo.x = f2bf_rne(acc[i][0] - bf2f(h));
        h = f2bf_rne(acc[i][1]); hi.y = h; lo.y = f2bf_rne(acc[i][1] - bf2f(h));
        h = f2bf_rne(acc[i][2]); hi.z = h; lo.z = f2bf_rne(acc[i][2] - bf2f(h));
        h = f2bf_rne(acc[i][3]); hi.w = h; lo.w = f2bf_rne(acc[i][3] - bf2f(h));
        const size_t o = ((size_t)n * 64 + c4 + i) * NV + v0 + v4;
        *(ushort4*)&Yh[o] = hi;
        *(ushort4*)&Yl[o] = lo;
    }
}

// ---------------------------------------------------------------------------
// Kernel 2: vertex->edge MFMA partials. No LDS, no barriers.
// A (cold HBM bit-words): prefetch DEPTH 4, static modulo-4 rotation.
// B (L2-warm Y^T fragments): prefetch depth 1 (2-slot rotation).
// ---------------------------------------------------------------------------
__global__ __launch_bounds__(256, 4) void k_v2e(const uint32_t* __restrict__ HT,
                                                const u16* __restrict__ Yh,
                                                const u16* __restrict__ Yl,
                                                float* __restrict__ P2) {
    const int n  = blockIdx.z;
    const int sp = blockIdx.y;
    const int e0 = blockIdx.x * 64;
    const int krange = NV / gridDim.y;
    const int kk0 = sp * krange;
    const int S   = krange / 32;   // multiple of 4, >= 8 for all tiers

    const int t = threadIdx.x, w = t >> 6, l = t & 63;
    const int lq = l >> 4, lr = l & 15;
    const int sh = lq * 8;
    const int hstride = (NV / 32) * 16;

    const uint32_t* __restrict__ ht =
        HT + ((size_t)n * (NE / 16) + (e0 >> 4)) * hstride + (kk0 >> 5) * 16 + lr;
    const u16* __restrict__ ybh = Yh + ((size_t)n * 64 + w * 16 + lr) * NV + kk0 + lq * 8;
    const u16* __restrict__ ybl = Yl + ((size_t)n * 64 + w * 16 + lr) * NV + kk0 + lq * 8;

    f32x4 acc0 = {0.f,0.f,0.f,0.f}, acc1 = acc0, acc2 = acc0, acc3 = acc0;

    // A pipeline: A[d] holds the 4 bit-words of step sb+d
    uint32_t A[4][4];
#pragma unroll
    for (int d = 0; d < 4; ++d) {
        A[d][0] = ht[0 * hstride + d * 16];
        A[d][1] = ht[1 * hstride + d * 16];
        A[d][2] = ht[2 * hstride + d * 16];
        A[d][3] = ht[3 * hstride + d * 16];
    }
    u16x8 BH[2], BL[2];
    BH[0] = *(const u16x8*)ybh;
    BL[0] = *(const u16x8*)ybl;

#define V2E_STEP(s, u, GUARD_A, GUARD_B)                                      \
    {                                                                         \
        const uint32_t a0 = A[u][0], a1 = A[u][1], a2 = A[u][2], a3 = A[u][3];\
        if (GUARD_A) {   /* reload A[u] for step s+4: issue EARLY */          \
            A[u][0] = ht[0 * hstride + ((s) + 4) * 16];                       \
            A[u][1] = ht[1 * hstride + ((s) + 4) * 16];                       \
            A[u][2] = ht[2 * hstride + ((s) + 4) * 16];                       \
            A[u][3] = ht[3 * hstride + ((s) + 4) * 16];                       \
        }                                                                     \
        if (GUARD_B) {                                                        \
            BH[((u) + 1) & 1] = *(const u16x8*)(ybh + ((s) + 1) * 32);        \
            BL[((u) + 1) & 1] = *(const u16x8*)(ybl + ((s) + 1) * 32);        \
        }                                                                     \
        const u16x8 bh = BH[(u) & 1], bl = BL[(u) & 1];                       \
        u16x8 a;                                                              \
        a = expand8((a0 >> sh) & 0xFF);                                       \
        acc0 = mfma_bf16(a, bh, acc0); acc0 = mfma_bf16(a, bl, acc0);         \
        a = expand8((a1 >> sh) & 0xFF);                                       \
        acc1 = mfma_bf16(a, bh, acc1); acc1 = mfma_bf16(a, bl, acc1);         \
        a = expand8((a2 >> sh) & 0xFF);                                       \
        acc2 = mfma_bf16(a, bh, acc2); acc2 = mfma_bf16(a, bl, acc2);         \
        a = expand8((a3 >> sh) & 0xFF);                                       \
        acc3 = mfma_bf16(a, bh, acc3); acc3 = mfma_bf16(a, bl, acc3);         \
    }

    int sb = 0;
    for (; sb < S - 4; sb += 4) {        // steady state: no guards false
        V2E_STEP(sb + 0, 0, true, true)
        V2E_STEP(sb + 1, 1, true, true)
        V2E_STEP(sb + 2, 2, true, true)
        V2E_STEP(sb + 3, 3, true, true)
    }
    // tail block sb = S-4
    V2E_STEP(sb + 0, 0, false, true)
    V2E_STEP(sb + 1, 1, false, true)
    V2E_STEP(sb + 2, 2, false, true)
    V2E_STEP(sb + 3, 3, false, false)
#undef V2E_STEP

    // D: row e = e0 + eb*16 + lq*4 + reg, col c = w*16 + lr
    float* pb = P2 + (((size_t)sp * N_B + n) * 64 + w * 16 + lr) * NE + e0 + lq * 4;
    *(f32x4*)(pb + 0)  = acc0;
    *(f32x4*)(pb + 16) = acc1;
    *(f32x4*)(pb + 32) = acc2;
    *(f32x4*)(pb + 48) = acc3;
}

// ---------------------------------------------------------------------------
// Kernel 3: Z_{h,l}[n][c][e] = bf16 hi/lo of (sum_sp P2)/de
// ---------------------------------------------------------------------------
__global__ __launch_bounds__(256) void k_red2(const float* __restrict__ P2,
                                              const float* __restrict__ de,
                                              u16* __restrict__ Zh,
                                              u16* __restrict__ Zl, int nsp) {
    const int i = blockIdx.x * 256 + threadIdx.x;   // 0..131071
    const int row = i >> 9;                          // n*64 + c
    const int e4  = (i & 511) * 4;
    const int n   = row >> 6;

    float4 a = make_float4(0.f, 0.f, 0.f, 0.f);
    for (int sp = 0; sp < nsp; ++sp) {
        const float4 p = *(const float4*)&P2[((size_t)sp * 256 + row) * NE + e4];
        a.x += p.x; a.y += p.y; a.z += p.z; a.w += p.w;
    }
    const float4 d = *(const float4*)&de[(size_t)n * NE + e4];
    float z[4] = {a.x / d.x, a.y / d.y, a.z / d.z, a.w / d.w};
    ushort4 hi, lo;
    u16 h;
    h = f2bf_rne(z[0]); hi.x = h; lo.x = f2bf_rne(z[0] - bf2f(h));
    h = f2bf_rne(z[1]); hi.y = h; lo.y = f2bf_rne(z[1] - bf2f(h));
    h = f2bf_rne(z[2]); hi.z = h; lo.z = f2bf_rne(z[2] - bf2f(h));
    h = f2bf_rne(z[3]); hi.w = h; lo.w = f2bf_rne(z[3] - bf2f(h));
    *(ushort4*)&Zh[(size_t)row * NE + e4] = hi;
    *(ushort4*)&Zl[(size_t)row * NE + e4] = lo;
}

// ---------------------------------------------------------------------------
// Kernel 4: edge->vertex MFMA partials. A depth-4, B depth-1, no LDS.
// ---------------------------------------------------------------------------
__global__ __launch_bounds__(256, 4) void k_e2v(const uint32_t* __restrict__ HB,
                                                const u16* __restrict__ Zh,
                                                const u16* __restrict__ Zl,
                                                float* __restrict__ P3) {
    const int n  = blockIdx.z;
    const int sp = blockIdx.y;
    const int v0 = blockIdx.x * 64;
    const int krange = NE / gridDim.y;
    const int kk0 = sp * krange;
    const int S   = krange / 32;   // multiple of 4, >= 8 for all tiers

    const int t = threadIdx.x, w = t >> 6, l = t & 63;
    const int lq = l >> 4, lr = l & 15;
    const int sh = lq * 8;
    const int estride = (NE / 32) * 16;

    const uint32_t* __restrict__ hb =
        HB + ((size_t)n * (NV / 16) + (v0 >> 4)) * estride + (kk0 >> 5) * 16 + lr;
    const u16* __restrict__ zbh = Zh + ((size_t)n * 64 + w * 16 + lr) * NE + kk0 + lq * 8;
    const u16* __restrict__ zbl = Zl + ((size_t)n * 64 + w * 16 + lr) * NE + kk0 + lq * 8;

    f32x4 acc0 = {0.f,0.f,0.f,0.f}, acc1 = acc0, acc2 = acc0, acc3 = acc0;

    uint32_t A[4][4];
#pragma unroll
    for (int d = 0; d < 4; ++d) {
        A[d][0] = hb[0 * estride + d * 16];
        A[d][1] = hb[1 * estride + d * 16];
        A[d][2] = hb[2 * estride + d * 16];
        A[d][3] = hb[3 * estride + d * 16];
    }
    u16x8 BH[2], BL[2];
    BH[0] = *(const u16x8*)zbh;
    BL[0] = *(const u16x8*)zbl;

#define E2V_STEP(s, u, GUARD_A, GUARD_B)                                      \
    {                                                                         \
        const uint32_t a0 = A[u][0], a1 = A[u][1], a2 = A[u][2], a3 = A[u][3];\
        if (GUARD_A) {                                                        \
            A[u][0] = hb[0 * estride + ((s) + 4) * 16];                       \
            A[u][1] = hb[1 * estride + ((s) + 4) * 16];                       \
            A[u][2] = hb[2 * estride + ((s) + 4) * 16];                       \
            A[u][3] = hb[3 * estride + ((s) + 4) * 16];                       \
        }                                                                     \
        if (GUARD_B) {                                                        \
            BH[((u) + 1) & 1] = *(const u16x8*)(zbh + ((s) + 1) * 32);        \
            BL[((u) + 1) & 1] = *(const u16x8*)(zbl + ((s) + 1) * 32);        \
        }                                                                     \
        const u16x8 bh = BH[(u) & 1], bl = BL[(u) & 1];                       \
        u16x8 a;                                                              \
        a = expand8((a0 >> sh) & 0xFF);                                       \
        acc0 = mfma_bf16(a, bh, acc0); acc0 = mfma_bf16(a, bl, acc0);         \
        a = expand8((a1 >> sh) & 0xFF);                                       \
        acc1 = mfma_bf16(a, bh, acc1); acc1 = mfma_bf16(a, bl, acc1);         \
        a = expand8((a2 >> sh) & 0xFF);                                       \
        acc2 = mfma_bf16(a, bh, acc2); acc2 = mfma_bf16(a, bl, acc2);         \
        a = expand8((a3 >> sh) & 0xFF);                                       \
        acc3 = mfma_bf16(a, bh, acc3); acc3 = mfma_bf16(a, bl, acc3);         \
    }

    int sb = 0;
    for (; sb < S - 4; sb += 4) {
        E2V_STEP(sb + 0, 0, true, true)
        E2V_STEP(sb + 1, 1, true, true)
        E2V_STEP(sb + 2, 2, true, true)
        E2V_STEP(sb + 3, 3, true, true)
    }
    E2V_STEP(sb + 0, 0, false, true)
    E2V_STEP(sb + 1, 1, false, true)
    E2V_STEP(sb + 2, 2, false, true)
    E2V_STEP(sb + 3, 3, false, false)
#undef E2V_STEP

    float* pb = P3 + (((size_t)sp * N_B + n) * 64 + w * 16 + lr) * NV + v0 + lq * 4;
    *(f32x4*)(pb + 0)  = acc0;
    *(f32x4*)(pb + 16) = acc1;
    *(f32x4*)(pb + 32) = acc2;
    *(f32x4*)(pb + 48) = acc3;
}

// ---------------------------------------------------------------------------
// Kernel 5: out[n][v][c] = (sum_sp P3[sp][n][c][v]) / dv + bias  (transpose)
// ---------------------------------------------------------------------------
__global__ __launch_bounds__(512) void k_red3(const float* __restrict__ P3,
                                              const float* __restrict__ dv,
                                              const float* __restrict__ bias,
                                              float* __restrict__ out, int nsp) {
    __shared__ float lt[64][68];
    const int n  = blockIdx.y;
    const int v0 = blockIdx.x * 64;
    const int t  = threadIdx.x;

    {
        const int c   = t >> 3;
        const int vch = (t & 7) * 8;
        float4 s0 = make_float4(0.f, 0.f, 0.f, 0.f), s1 = s0;
        for (int sp = 0; sp < nsp; ++sp) {
            const size_t base = (((size_t)sp * N_B + n) * 64 + c) * NV + v0 + vch;
            const float4 p0 = *(const float4*)&P3[base];
            const float4 p1 = *(const float4*)&P3[base + 4];
            s0.x += p0.x; s0.y += p0.y; s0.z += p0.z; s0.w += p0.w;
            s1.x += p1.x; s1.y += p1.y; s1.z += p1.z; s1.w += p1.w;
        }
        *(float4*)&lt[c][vch]     = s0;
        *(float4*)&lt[c][vch + 4] = s1;
    }
    const int vw  = t >> 3;
    const int cch = (t & 7) * 8;
    const float dsum = dv[(size_t)n * NV + v0 + vw];
    __syncthreads();

    const float rdv = 1.0f / dsum;
    const float4 b0 = *(const float4*)&bias[cch];
    const float4 b1 = *(const float4*)&bias[cch + 4];
    float4 o0, o1;
    o0.x = lt[cch + 0][vw] * rdv + b0.x;
    o0.y = lt[cch + 1][vw] * rdv + b0.y;
    o0.z = lt[cch + 2][vw] * rdv + b0.z;
    o0.w = lt[cch + 3][vw] * rdv + b0.w;
    o1.x = lt[cch + 4][vw] * rdv + b1.x;
    o1.y = lt[cch + 5][vw] * rdv + b1.y;
    o1.z = lt[cch + 6][vw] * rdv + b1.z;
    o1.w = lt[cch + 7][vw] * rdv + b1.w;
    float* dst = out + ((size_t)n * NV + v0 + vw) * 64 + cch;
    *(float4*)dst       = o0;
    *(float4*)(dst + 4) = o1;
}

// ---------------------------------------------------------------------------
extern "C" void kernel_launch(void* const* d_in, const int* in_sizes, int n_in,
                              void* d_out, int out_size, void* d_ws, size_t ws_size,
                              hipStream_t stream) {
    const float* x     = (const float*)d_in[0];
    const float* H     = (const float*)d_in[1];
    const float* theta = (const float*)d_in[2];
    const float* bias  = (const float*)d_in[3];
    float* out = (float*)d_out;

    const size_t yE   = (size_t)N_B * 64 * NV;
    const size_t zE   = (size_t)N_B * 64 * NE;
    const size_t HBW  = (size_t)N_B * (NV / 16) * (NE / 32) * 16;
    const size_t HTW  = (size_t)N_B * (NE / 16) * (NV / 32) * 16;
    const size_t depE = (size_t)64 * N_B * NE;
    const size_t dvpE = (size_t)32 * N_B * NV;
    const size_t deE  = (size_t)N_B * NE;
    const size_t dvE  = (size_t)N_B * NV;

    u16* Yh = (u16*)d_ws;
    u16* Yl = Yh + yE;
    u16* Zh = Yl + yE;
    u16* Zl = Zh + zE;
    uint32_t* HB = (uint32_t*)(Zl + zE);
    uint32_t* HT = HB + HBW;
    float* deP = (float*)(HT + HTW);
    float* dvP = deP + depE;
    float* de  = dvP + dvpE;
    float* dv  = de + deE;
    float* fbase = dv + dvE;

    const size_t fixed_bytes = (size_t)((char*)fbase - (char*)d_ws);
    const size_t avail_f = (ws_size > fixed_bytes) ? (ws_size - fixed_bytes) / 4 : 0;

    const size_t unit2 = zE;
    const size_t unit3 = yE;
    // s2/s3 tiers chosen so S = (K/splits)/32 is a multiple of 4 and >= 8
    int s2 = 1, s3 = 1;
    if      (avail_f >= 8 * unit2 + 4 * unit3) { s2 = 8; s3 = 4; }
    else if (avail_f >= 4 * unit2 + 2 * unit3) { s2 = 4; s3 = 2; }
    else if (avail_f >= 2 * unit2 + 1 * unit3) { s2 = 2; s3 = 1; }

    float* P2 = fbase;
    float* P3 = P2 + (size_t)s2 * zE;

    k_pack<<<dim3(NE / 64, NV / 64, N_B), 256, 0, stream>>>(H, HB, HT, dvP, deP);
    k_xtheta<<<dim3(N_B * NV / 64), 256, 0, stream>>>(x, theta, Yh, Yl);
    k_deg<<<dim3((N_B * NE + N_B * NV) / 256), 256, 0, stream>>>(dvP, deP, dv, de);
    k_v2e<<<dim3(NE / 64, s2, N_B), 256, 0, stream>>>(HT, Yh, Yl, P2);
    k_red2<<<dim3((int)(zE / 4 / 256)), 256, 0, stream>>>(P2, de, Zh, Zl, s2);
    k_e2v<<<dim3(NV / 64, s3, N_B), 256, 0, stream>>>(HB, Zh, Zl, P3);
    k_red3<<<dim3(NV / 64, N_B), 512, 0, stream>>>(P3, dv, bias, out, s3);
}